// Round 8
// baseline (278.944 us; speedup 1.0000x reference)
//
#include <hip/hip_runtime.h>
#include <stdint.h>

#define N_VOX 262144
#define CCH 64
#define KOFF 27

typedef short v8s __attribute__((ext_vector_type(8)));
typedef float v4f __attribute__((ext_vector_type(4)));

__device__ __forceinline__ unsigned short f2bf(float f) {
  unsigned u = __float_as_uint(f);
  u += 0x7fff + ((u >> 16) & 1);   // RNE
  return (unsigned short)(u >> 16);
}

// --- deterministic sniff of the mask buffer's dtype (byte-bool vs 32-bit) ---
__global__ void prep_flag_k(const unsigned* __restrict__ m, int* __restrict__ flag) {
  if (threadIdx.x == 0) {
    int wordlike = 1;  // int32 0/1 or float32 0.0/1.0
    for (int i = 0; i < 256; ++i) {
      unsigned v = m[i];
      if (v > 1u && v != 0x3f800000u) { wordlike = 0; break; }
    }
    *flag = wordlike ? 0 : 2;   // 0: read as u32 words, 2: read as bytes
  }
}

__global__ void prep_mask_k(const void* __restrict__ m, const int* __restrict__ flag,
                            unsigned char* __restrict__ mb, int n) {
  int f = *flag;
  for (int i = blockIdx.x * blockDim.x + threadIdx.x; i < n; i += gridDim.x * blockDim.x) {
    unsigned char v;
    if (f == 2) v = (((const unsigned char*)m)[i] != 0);
    else        v = (((const unsigned*)m)[i] != 0u);
    mb[i] = v;
  }
}

// --- features fp32 -> bf16 table ---
__global__ void prep_feat_k(const float* __restrict__ src, unsigned short* __restrict__ dst, int n8) {
  int i = blockIdx.x * blockDim.x + threadIdx.x;
  if (i >= n8) return;
  const float4* s4 = (const float4*)src;
  float4 a = s4[i * 2], b = s4[i * 2 + 1];
  v8s v;
  v[0] = (short)f2bf(a.x); v[1] = (short)f2bf(a.y);
  v[2] = (short)f2bf(a.z); v[3] = (short)f2bf(a.w);
  v[4] = (short)f2bf(b.x); v[5] = (short)f2bf(b.y);
  v[6] = (short)f2bf(b.z); v[7] = (short)f2bf(b.w);
  ((v8s*)dst)[i] = v;
}

// --- W [27][cin][cout] fp32 -> frag-order bf16: wf[k][ch][lane][8], where
// ch = coltile*2 + half; lane's 8 elems = cin (half*32 + (lane>>4)*8 + e),
// col = coltile*16 + (lane&15). Staging copy AND B-frag ds_reads are linear. ---
__global__ void prep_w_k(const float* __restrict__ w, unsigned short* __restrict__ wt) {
  int i = blockIdx.x * blockDim.x + threadIdx.x;
  if (i >= KOFF * CCH * CCH) return;          // 110592
  int e = i & 7, lane = (i >> 3) & 63, ch = (i >> 9) & 7, k = i >> 12;
  int ct = ch >> 1, half = ch & 1;
  int col = ct * 16 + (lane & 15);
  int kk = half * 32 + ((lane >> 4) << 3) + e;
  wt[i] = f2bf(w[(k << 12) + (kk << 6) + col]);
}

// One body (k-th offset). Consumes A(k) [gathered last body, set Ac] and
// W(k) [in LDS buffer Wc]. Issues, in FIFO order: W(k+1) global load,
// gathers A(k+1)->An, idx/mask(k+2). MFMAs depend on none of those, so the
// only vmem wait this body is next body's counted wait for the gathers.
// Ends with ds_write W(k+1)->Wn + lgkm-only barrier (gathers stay in flight).
__device__ __forceinline__ void conv_body(
    int k, const v8s* __restrict__ Wc, v8s* __restrict__ Wn,
    const v8s* __restrict__ src8, const int* __restrict__ nbr,
    const unsigned char* __restrict__ mb, const v8s* __restrict__ wfg,
    int tid, int lane, int g,
    int r0, int r1, int r2, int r3,
    v8s (&Ac)[8], v8s (&An)[8],
    int& j0, int& j1, int& j2, int& j3,
    int& n0, int& n1, int& n2, int& n3,
    v4f (&acc)[4][4])
{
  const bool more = (k + 1 < KOFF);

  // 1. W(k+1) global prefetch (oldest vmem this body)
  v8s w0 = {}, w1 = {};
  if (more) {
    w0 = wfg[(k + 1) * 512 + tid];
    w1 = wfg[(k + 1) * 512 + 256 + tid];
  }

  // 2. gathers A(k+1) -> An (consumed next body; masked rows skipped),
  //    then refill idx/mask(k+2) into j/n (consumed next body)
  if (more) {
    An[0] = (v8s){}; An[1] = (v8s){}; An[2] = (v8s){}; An[3] = (v8s){};
    An[4] = (v8s){}; An[5] = (v8s){}; An[6] = (v8s){}; An[7] = (v8s){};
    if (n0) { An[0] = src8[j0 * 8 + g]; An[1] = src8[j0 * 8 + 4 + g]; }
    if (n1) { An[2] = src8[j1 * 8 + g]; An[3] = src8[j1 * 8 + 4 + g]; }
    if (n2) { An[4] = src8[j2 * 8 + g]; An[5] = src8[j2 * 8 + 4 + g]; }
    if (n3) { An[6] = src8[j3 * 8 + g]; An[7] = src8[j3 * 8 + 4 + g]; }
    const int kj = (k + 2 < KOFF) ? k + 2 : KOFF - 1;
    j0 = nbr[kj * N_VOX + r0]; j1 = nbr[kj * N_VOX + r1];
    j2 = nbr[kj * N_VOX + r2]; j3 = nbr[kj * N_VOX + r3];
    n0 = mb[kj * N_VOX + r0];  n1 = mb[kj * N_VOX + r1];
    n2 = mb[kj * N_VOX + r2];  n3 = mb[kj * N_VOX + r3];
  }

  // 3. MFMA: B-frags JIT from LDS per coltile (keeps peak regs under the cap)
#pragma unroll
  for (int ct = 0; ct < 4; ++ct) {
    v8s blo = Wc[(ct * 2) * 64 + lane];
    v8s bhi = Wc[(ct * 2 + 1) * 64 + lane];
#pragma unroll
    for (int rt = 0; rt < 4; ++rt) {
      acc[rt][ct] = __builtin_amdgcn_mfma_f32_16x16x32_bf16(Ac[2 * rt],     blo, acc[rt][ct], 0, 0, 0);
      acc[rt][ct] = __builtin_amdgcn_mfma_f32_16x16x32_bf16(Ac[2 * rt + 1], bhi, acc[rt][ct], 0, 0, 0);
    }
  }

  // 4. stage W(k+1); lgkm-only barrier (gathers cross it in flight)
  if (more) {
    Wn[tid] = w0;
    Wn[256 + tid] = w1;
    asm volatile("s_waitcnt lgkmcnt(0)" ::: "memory");
    __builtin_amdgcn_s_barrier();
  }
}

// --- one sparse-conv layer: 4 waves x 64 rows, even/odd A-sets (no copies),
// W double-buffered in LDS, one lgkm-only barrier per body. ---
template <int LAYER>
__global__ __launch_bounds__(256, 3)
void conv_layer_k(const v8s* __restrict__ src8, const int* __restrict__ nbr,
                  const unsigned char* __restrict__ mb,
                  const v8s* __restrict__ wfg, const float* __restrict__ bias,
                  const float* __restrict__ resid, void* __restrict__ outp) {
  __shared__ v8s ldsW[2][512];   // 2 x 8 KiB
  const int tid = threadIdx.x;
  const int lane = tid & 63;
  const int wv = tid >> 6;
  const int l15 = lane & 15;
  const int g = lane >> 4;
  const int rowbase = blockIdx.x * 256 + wv * 64;
  const int r0 = rowbase + l15;
  const int r1 = r0 + 16;
  const int r2 = r0 + 32;
  const int r3 = r0 + 48;

  // ---- prologue: A(0)->AE, idx/mask(1)->j/n, W(0)->ldsW[0] ----
  int j0 = nbr[r0], j1 = nbr[r1], j2 = nbr[r2], j3 = nbr[r3];
  int n0 = mb[r0], n1 = mb[r1], n2 = mb[r2], n3 = mb[r3];

  v8s AE[8] = {}, AO[8] = {};
  if (n0) { AE[0] = src8[j0 * 8 + g]; AE[1] = src8[j0 * 8 + 4 + g]; }
  if (n1) { AE[2] = src8[j1 * 8 + g]; AE[3] = src8[j1 * 8 + 4 + g]; }
  if (n2) { AE[4] = src8[j2 * 8 + g]; AE[5] = src8[j2 * 8 + 4 + g]; }
  if (n3) { AE[6] = src8[j3 * 8 + g]; AE[7] = src8[j3 * 8 + 4 + g]; }

  j0 = nbr[N_VOX + r0]; j1 = nbr[N_VOX + r1];
  j2 = nbr[N_VOX + r2]; j3 = nbr[N_VOX + r3];
  n0 = mb[N_VOX + r0];  n1 = mb[N_VOX + r1];
  n2 = mb[N_VOX + r2];  n3 = mb[N_VOX + r3];

  ldsW[0][tid] = wfg[tid];
  ldsW[0][256 + tid] = wfg[256 + tid];
  asm volatile("s_waitcnt lgkmcnt(0)" ::: "memory");
  __builtin_amdgcn_s_barrier();

  v4f acc[4][4] = {};

#pragma unroll 1
  for (int k = 0; k < KOFF - 1; k += 2) {
    conv_body(k,     ldsW[0], ldsW[1], src8, nbr, mb, wfg, tid, lane, g,
              r0, r1, r2, r3, AE, AO, j0, j1, j2, j3, n0, n1, n2, n3, acc);
    conv_body(k + 1, ldsW[1], ldsW[0], src8, nbr, mb, wfg, tid, lane, g,
              r0, r1, r2, r3, AO, AE, j0, j1, j2, j3, n0, n1, n2, n3, acc);
  }
  conv_body(KOFF - 1, ldsW[0], ldsW[1], src8, nbr, mb, wfg, tid, lane, g,
            r0, r1, r2, r3, AE, AO, j0, j1, j2, j3, n0, n1, n2, n3, acc);

  float bv[4];
#pragma unroll
  for (int ct = 0; ct < 4; ++ct) bv[ct] = bias[ct * 16 + l15];

#pragma unroll
  for (int rt = 0; rt < 4; ++rt) {
    int row0 = rowbase + rt * 16 + g * 4;   // D row = (lane>>4)*4 + i
#pragma unroll
    for (int ct = 0; ct < 4; ++ct) {
      int col = ct * 16 + l15;              // D col = lane & 15
#pragma unroll
      for (int i = 0; i < 4; ++i) {
        float v = acc[rt][ct][i] + bv[ct];
        int o = (row0 + i) * CCH + col;
        if (LAYER == 1) ((unsigned short*)outp)[o] = f2bf(v);
        else            ((float*)outp)[o] = v + resid[o];
      }
    }
  }
}

extern "C" void kernel_launch(void* const* d_in, const int* in_sizes, int n_in,
                              void* d_out, int out_size, void* d_ws, size_t ws_size,
                              hipStream_t stream) {
  const float* feat = (const float*)d_in[0];
  const int* nbr    = (const int*)d_in[1];
  const void* mask  = d_in[2];
  const float* w1   = (const float*)d_in[3];
  const float* b1   = (const float*)d_in[4];
  const float* w2   = (const float*)d_in[5];
  const float* b2   = (const float*)d_in[6];

  char* ws = (char*)d_ws;
  unsigned short* featb = (unsigned short*)ws;                    // 33,554,432 B
  unsigned short* hb    = (unsigned short*)(ws + 33554432);       // 33,554,432 B
  unsigned char*  maskb = (unsigned char*)(ws + 67108864);        //  7,077,888 B
  unsigned short* wf1   = (unsigned short*)(ws + 74186752);       //    221,184 B
  unsigned short* wf2   = (unsigned short*)(ws + 74407936);       //    221,184 B
  int*            flag  = (int*)(ws + 74629120);

  prep_flag_k<<<1, 64, 0, stream>>>((const unsigned*)mask, flag);
  prep_mask_k<<<4096, 256, 0, stream>>>(mask, flag, maskb, KOFF * N_VOX);
  prep_feat_k<<<8192, 256, 0, stream>>>(feat, featb, N_VOX * CCH / 8);
  prep_w_k<<<432, 256, 0, stream>>>(w1, wf1);
  prep_w_k<<<432, 256, 0, stream>>>(w2, wf2);

  conv_layer_k<1><<<1024, 256, 0, stream>>>((const v8s*)featb, nbr, maskb,
                                            (const v8s*)wf1, b1, nullptr, (void*)hb);
  conv_layer_k<2><<<1024, 256, 0, stream>>>((const v8s*)hb, nbr, maskb,
                                            (const v8s*)wf2, b2, feat, (void*)d_out);
}

// Round 9
// 250.287 us; speedup vs baseline: 1.1145x; 1.1145x over previous
//
#include <hip/hip_runtime.h>
#include <stdint.h>

#define N_VOX 262144
#define CCH 64
#define KOFF 27

typedef short v8s __attribute__((ext_vector_type(8)));
typedef float v4f __attribute__((ext_vector_type(4)));

// global -> LDS DMA, 16B/lane. LDS dest = wave-uniform base + lane*16 (m104);
// global src is per-lane. All call sites issue with FULL exec (no divergence)
// so vmcnt bookkeeping is exact.
#define GLD16(gp, lp) __builtin_amdgcn_global_load_lds(                     \
    (const __attribute__((address_space(1))) void*)(gp),                    \
    (__attribute__((address_space(3))) void*)(lp), 16, 0, 0)

__device__ __forceinline__ unsigned short f2bf(float f) {
  unsigned u = __float_as_uint(f);
  u += 0x7fff + ((u >> 16) & 1);   // RNE
  return (unsigned short)(u >> 16);
}

// --- deterministic sniff of the mask buffer's dtype (byte-bool vs 32-bit) ---
__global__ void prep_flag_k(const unsigned* __restrict__ m, int* __restrict__ flag) {
  if (threadIdx.x == 0) {
    int wordlike = 1;  // int32 0/1 or float32 0.0/1.0
    for (int i = 0; i < 256; ++i) {
      unsigned v = m[i];
      if (v > 1u && v != 0x3f800000u) { wordlike = 0; break; }
    }
    *flag = wordlike ? 0 : 2;   // 0: read as u32 words, 2: read as bytes
  }
}

__global__ void prep_mask_k(const void* __restrict__ m, const int* __restrict__ flag,
                            unsigned char* __restrict__ mb, int n) {
  int f = *flag;
  for (int i = blockIdx.x * blockDim.x + threadIdx.x; i < n; i += gridDim.x * blockDim.x) {
    unsigned char v;
    if (f == 2) v = (((const unsigned char*)m)[i] != 0);
    else        v = (((const unsigned*)m)[i] != 0u);
    mb[i] = v;
  }
}

// --- features fp32 -> bf16 table ---
__global__ void prep_feat_k(const float* __restrict__ src, unsigned short* __restrict__ dst, int n8) {
  int i = blockIdx.x * blockDim.x + threadIdx.x;
  if (i >= n8) return;
  const float4* s4 = (const float4*)src;
  float4 a = s4[i * 2], b = s4[i * 2 + 1];
  v8s v;
  v[0] = (short)f2bf(a.x); v[1] = (short)f2bf(a.y);
  v[2] = (short)f2bf(a.z); v[3] = (short)f2bf(a.w);
  v[4] = (short)f2bf(b.x); v[5] = (short)f2bf(b.y);
  v[6] = (short)f2bf(b.z); v[7] = (short)f2bf(b.w);
  ((v8s*)dst)[i] = v;
}

// --- W [27][cin][cout] fp32 -> frag-order bf16: wf[k][ct*2+half][lane][8].
// Both the LDS DMA copy and per-lane B-fragment ds_reads are fully linear. ---
__global__ void prep_w_k(const float* __restrict__ w, unsigned short* __restrict__ wt) {
  int i = blockIdx.x * blockDim.x + threadIdx.x;
  if (i >= KOFF * CCH * CCH) return;          // 110592
  int e = i & 7, lane = (i >> 3) & 63, ch = (i >> 9) & 7, k = i >> 12;
  int ct = ch >> 1, half = ch & 1;
  int col = ct * 16 + (lane & 15);
  int kk = half * 32 + ((lane >> 4) << 3) + e;
  wt[i] = f2bf(w[(k << 12) + (kk << 6) + col]);
}

// One body (offset k). Per-body VMEM issue order (9 ops, full exec, fixed):
//   [W(k+1) DMA x1][A(k+1) DMA x4][idx/mask(k+2) reload x4]
// Waits:  top vmcnt(4)  = W(k)+A(k) landed, reloads stay in flight
//         pre-barrier vmcnt(8) = own W(k+1) DMA landed (cross-wave dbuf safety)
// A-gathers cross the barrier in flight; their wait is next body's vmcnt(4).
__device__ __forceinline__ void conv_body(
    int k, bool last, char* slot, const v8s* __restrict__ Wc, char* WnB,
    const char* __restrict__ src8B, const char* __restrict__ wfgB,
    const int* __restrict__ nbr, const unsigned char* __restrict__ mb,
    int lane, int g, int tid16, int r0, int r1,
    int& jz0, int& jz1, int& mz0, int& mz1,   // zero-mask here, then reload (k+2)
    int jd0, int jd1, int md0, int md1,       // DMA-addr set (loaded last body)
    v4f (&acc)[2][4])
{
  asm volatile("s_waitcnt vmcnt(4)" ::: "memory");   // A(k)+W(k) DMAs landed
  v8s a0 = *(const v8s*)(slot + lane * 16);
  v8s a1 = *(const v8s*)(slot + 1024 + lane * 16);
  v8s a2 = *(const v8s*)(slot + 2048 + lane * 16);
  v8s a3 = *(const v8s*)(slot + 3072 + lane * 16);
  if (!mz0) { a0 = (v8s){}; a1 = (v8s){}; }          // dummy-fetched rows -> 0
  if (!mz1) { a2 = (v8s){}; a3 = (v8s){}; }
  asm volatile("s_waitcnt lgkmcnt(0)" ::: "memory"); // reads retired before slot reuse
  __builtin_amdgcn_sched_barrier(0);

  if (!last) {
    // W(k+1): this wave's 1KB portion of the other W buffer
    GLD16(wfgB + (size_t)(k + 1) * 8192 + tid16, WnB);
    // A(k+1): full-exec gathers; masked rows read row 0 (L1-hot dummy)
    long e0 = (long)(md0 ? jd0 : 0) * 128 + g * 16;
    long e1 = (long)(md1 ? jd1 : 0) * 128 + g * 16;
    GLD16(src8B + e0,      slot);
    GLD16(src8B + e0 + 64, slot + 1024);
    GLD16(src8B + e1,      slot + 2048);
    GLD16(src8B + e1 + 64, slot + 3072);
    // idx/mask(k+2) reload into the set just consumed for zeroing
    const int kj = (k + 2 < KOFF) ? k + 2 : KOFF - 1;
    jz0 = nbr[kj * N_VOX + r0]; jz1 = nbr[kj * N_VOX + r1];
    mz0 = mb[kj * N_VOX + r0];  mz1 = mb[kj * N_VOX + r1];
  }

#pragma unroll
  for (int ct = 0; ct < 4; ++ct) {
    v8s blo = Wc[ct * 128 + lane];
    v8s bhi = Wc[ct * 128 + 64 + lane];
    acc[0][ct] = __builtin_amdgcn_mfma_f32_16x16x32_bf16(a0, blo, acc[0][ct], 0, 0, 0);
    acc[0][ct] = __builtin_amdgcn_mfma_f32_16x16x32_bf16(a1, bhi, acc[0][ct], 0, 0, 0);
    acc[1][ct] = __builtin_amdgcn_mfma_f32_16x16x32_bf16(a2, blo, acc[1][ct], 0, 0, 0);
    acc[1][ct] = __builtin_amdgcn_mfma_f32_16x16x32_bf16(a3, bhi, acc[1][ct], 0, 0, 0);
  }

  if (!last) {
    asm volatile("s_waitcnt vmcnt(8)" ::: "memory"); // own W(k+1) DMA done
    __builtin_amdgcn_s_barrier();                    // A-DMAs stay in flight
  }
}

// --- one sparse-conv layer: 8 waves x 32 rows, A via per-wave LDS DMA ring
// (zero pipeline VGPRs), W dbuf via DMA, counted vmcnt, 16 waves/CU. ---
template <int LAYER>
__global__ __launch_bounds__(512, 4)
void conv_layer_k(const char* __restrict__ src8B, const int* __restrict__ nbr,
                  const unsigned char* __restrict__ mb,
                  const char* __restrict__ wfgB, const float* __restrict__ bias,
                  const float* __restrict__ resid, void* __restrict__ outp) {
  __shared__ char ldsW[2][8192];   // W(k) dbuf, shared by 8 waves
  __shared__ char ldsA[8][4096];   // per-wave gather ring slot
  const int tid = threadIdx.x;
  const int lane = tid & 63;
  const int wv = tid >> 6;
  const int l15 = lane & 15;
  const int g = lane >> 4;
  const int tid16 = tid * 16;
  const int rowbase = blockIdx.x * 256 + wv * 32;
  const int r0 = rowbase + l15;
  const int r1 = r0 + 16;
  char* slot = ldsA[wv];

  // ---- prologue: idx/mask(0)->E, A(0) DMA, W(0) DMA, idx/mask(1)->O ----
  int jE0 = nbr[r0], jE1 = nbr[r1];
  int mE0 = mb[r0],  mE1 = mb[r1];
  {
    long e0 = (long)(mE0 ? jE0 : 0) * 128 + g * 16;
    long e1 = (long)(mE1 ? jE1 : 0) * 128 + g * 16;
    GLD16(src8B + e0,      slot);
    GLD16(src8B + e0 + 64, slot + 1024);
    GLD16(src8B + e1,      slot + 2048);
    GLD16(src8B + e1 + 64, slot + 3072);
  }
  GLD16(wfgB + tid16, (char*)ldsW[0] + wv * 1024);
  int jO0 = nbr[N_VOX + r0], jO1 = nbr[N_VOX + r1];
  int mO0 = mb[N_VOX + r0],  mO1 = mb[N_VOX + r1];
  asm volatile("s_waitcnt vmcnt(0)" ::: "memory");
  __builtin_amdgcn_s_barrier();

  v4f acc[2][4] = {};

#pragma unroll 1
  for (int k = 0; k < KOFF - 1; k += 2) {
    conv_body(k, false, slot, (const v8s*)ldsW[0], (char*)ldsW[1] + wv * 1024,
              src8B, wfgB, nbr, mb, lane, g, tid16, r0, r1,
              jE0, jE1, mE0, mE1, jO0, jO1, mO0, mO1, acc);
    conv_body(k + 1, false, slot, (const v8s*)ldsW[1], (char*)ldsW[0] + wv * 1024,
              src8B, wfgB, nbr, mb, lane, g, tid16, r0, r1,
              jO0, jO1, mO0, mO1, jE0, jE1, mE0, mE1, acc);
  }
  conv_body(KOFF - 1, true, slot, (const v8s*)ldsW[0], (char*)ldsW[1] + wv * 1024,
            src8B, wfgB, nbr, mb, lane, g, tid16, r0, r1,
            jE0, jE1, mE0, mE1, jO0, jO1, mO0, mO1, acc);

  float bv[4];
#pragma unroll
  for (int ct = 0; ct < 4; ++ct) bv[ct] = bias[ct * 16 + l15];

#pragma unroll
  for (int rt = 0; rt < 2; ++rt) {
    int row0 = rowbase + rt * 16 + g * 4;   // D row = (lane>>4)*4 + i
#pragma unroll
    for (int ct = 0; ct < 4; ++ct) {
      int col = ct * 16 + l15;              // D col = lane & 15
#pragma unroll
      for (int i = 0; i < 4; ++i) {
        float v = acc[rt][ct][i] + bv[ct];
        int o = (row0 + i) * CCH + col;
        if (LAYER == 1) ((unsigned short*)outp)[o] = f2bf(v);
        else            ((float*)outp)[o] = v + resid[o];
      }
    }
  }
}

extern "C" void kernel_launch(void* const* d_in, const int* in_sizes, int n_in,
                              void* d_out, int out_size, void* d_ws, size_t ws_size,
                              hipStream_t stream) {
  const float* feat = (const float*)d_in[0];
  const int* nbr    = (const int*)d_in[1];
  const void* mask  = d_in[2];
  const float* w1   = (const float*)d_in[3];
  const float* b1   = (const float*)d_in[4];
  const float* w2   = (const float*)d_in[5];
  const float* b2   = (const float*)d_in[6];

  char* ws = (char*)d_ws;
  unsigned short* featb = (unsigned short*)ws;                    // 33,554,432 B
  unsigned short* hb    = (unsigned short*)(ws + 33554432);       // 33,554,432 B
  unsigned char*  maskb = (unsigned char*)(ws + 67108864);        //  7,077,888 B
  unsigned short* wf1   = (unsigned short*)(ws + 74186752);       //    221,184 B
  unsigned short* wf2   = (unsigned short*)(ws + 74407936);       //    221,184 B
  int*            flag  = (int*)(ws + 74629120);

  prep_flag_k<<<1, 64, 0, stream>>>((const unsigned*)mask, flag);
  prep_mask_k<<<4096, 256, 0, stream>>>(mask, flag, maskb, KOFF * N_VOX);
  prep_feat_k<<<8192, 256, 0, stream>>>(feat, featb, N_VOX * CCH / 8);
  prep_w_k<<<432, 256, 0, stream>>>(w1, wf1);
  prep_w_k<<<432, 256, 0, stream>>>(w2, wf2);

  conv_layer_k<1><<<1024, 512, 0, stream>>>((const char*)featb, nbr, maskb,
                                            (const char*)wf1, b1, nullptr, (void*)hb);
  conv_layer_k<2><<<1024, 512, 0, stream>>>((const char*)hb, nbr, maskb,
                                            (const char*)wf2, b2, feat, (void*)d_out);
}

// Round 10
// 243.614 us; speedup vs baseline: 1.1450x; 1.0274x over previous
//
#include <hip/hip_runtime.h>
#include <stdint.h>

#define N_VOX 262144
#define CCH 64
#define KOFF 27

typedef short v8s __attribute__((ext_vector_type(8)));
typedef float v4f __attribute__((ext_vector_type(4)));

// global -> LDS DMA, 16B/lane; LDS dest = wave-uniform base + lane*16 (m104).
// Always issued with FULL exec so vmcnt bookkeeping is static.
#define GLD16(gp, lp) __builtin_amdgcn_global_load_lds(                     \
    (const __attribute__((address_space(1))) void*)(gp),                    \
    (__attribute__((address_space(3))) void*)(lp), 16, 0, 0)

__device__ __forceinline__ unsigned short f2bf(float f) {
  unsigned u = __float_as_uint(f);
  u += 0x7fff + ((u >> 16) & 1);   // RNE
  return (unsigned short)(u >> 16);
}

// --- deterministic sniff of the mask buffer's dtype (byte-bool vs 32-bit) ---
__global__ void prep_flag_k(const unsigned* __restrict__ m, int* __restrict__ flag) {
  if (threadIdx.x == 0) {
    int wordlike = 1;  // int32 0/1 or float32 0.0/1.0
    for (int i = 0; i < 256; ++i) {
      unsigned v = m[i];
      if (v > 1u && v != 0x3f800000u) { wordlike = 0; break; }
    }
    *flag = wordlike ? 0 : 2;   // 0: read as u32 words, 2: read as bytes
  }
}

__global__ void prep_mask_k(const void* __restrict__ m, const int* __restrict__ flag,
                            unsigned char* __restrict__ mb, int n) {
  int f = *flag;
  for (int i = blockIdx.x * blockDim.x + threadIdx.x; i < n; i += gridDim.x * blockDim.x) {
    unsigned char v;
    if (f == 2) v = (((const unsigned char*)m)[i] != 0);
    else        v = (((const unsigned*)m)[i] != 0u);
    mb[i] = v;
  }
}

// --- features fp32 -> bf16 table ---
__global__ void prep_feat_k(const float* __restrict__ src, unsigned short* __restrict__ dst, int n8) {
  int i = blockIdx.x * blockDim.x + threadIdx.x;
  if (i >= n8) return;
  const float4* s4 = (const float4*)src;
  float4 a = s4[i * 2], b = s4[i * 2 + 1];
  v8s v;
  v[0] = (short)f2bf(a.x); v[1] = (short)f2bf(a.y);
  v[2] = (short)f2bf(a.z); v[3] = (short)f2bf(a.w);
  v[4] = (short)f2bf(b.x); v[5] = (short)f2bf(b.y);
  v[6] = (short)f2bf(b.z); v[7] = (short)f2bf(b.w);
  ((v8s*)dst)[i] = v;
}

// --- W [27][cin][cout] fp32 -> frag-order bf16: wf[k][ct*2+half][lane][8] ---
__global__ void prep_w_k(const float* __restrict__ w, unsigned short* __restrict__ wt) {
  int i = blockIdx.x * blockDim.x + threadIdx.x;
  if (i >= KOFF * CCH * CCH) return;          // 110592
  int e = i & 7, lane = (i >> 3) & 63, ch = (i >> 9) & 7, k = i >> 12;
  int ct = ch >> 1, half = ch & 1;
  int col = ct * 16 + (lane & 15);
  int kk = half * 32 + ((lane >> 4) << 3) + e;
  wt[i] = f2bf(w[(k << 12) + (kk << 6) + col]);
}

// One body (offset k). VMEM issue order (static, full exec):
//   [Wreg(k+1) x2][A(k+1) DMA x4][idx(k+2) x1][mask(k+2) x1]
// Entry in-flight: [A(k)x4][idx(k+1)][mask(k+1)] = 6.
// Waits: top vmcnt(2) (A landed), post-Wissue vmcnt(2) (idx/mask landed,
// Wreg flies), ds_write's compiler vmcnt (Wreg only). A-DMAs cross both
// barriers in flight; consumed at next body's top wait.
__device__ __forceinline__ void conv_body(
    int k, bool last, char* Wb, char* slotC, char* slotN,
    const char* __restrict__ src8B, const v8s* __restrict__ wfg,
    const int* __restrict__ nbr, const unsigned char* __restrict__ mb,
    int lane, int wv, int g, int l15, int rme,
    int& iN, int& mN, int& mc0, int& mc1,
    v4f (&acc)[2][4])
{
  asm volatile("s_waitcnt vmcnt(2)" ::: "memory");   // A(k) landed
  v8s w0, w1;
  int v0 = 0, v1 = 0;
  if (!last) {
    w0 = wfg[(k + 1) * 512 + wv * 128 + lane];       // W(k+1) -> regs (T14 issue)
    w1 = wfg[(k + 1) * 512 + wv * 128 + 64 + lane];
    asm volatile("s_waitcnt vmcnt(2)" ::: "memory"); // idx/mask(k+1) landed
    int j0 = __shfl(iN, l15, 64);
    int j1 = __shfl(iN, 16 + l15, 64);
    v0 = __shfl(mN, l15, 64);
    v1 = __shfl(mN, 16 + l15, 64);
    long e0 = (long)(v0 ? j0 : 0) * 128 + g * 16;    // masked -> row0 (hot dummy)
    long e1 = (long)(v1 ? j1 : 0) * 128 + g * 16;
    GLD16(src8B + e0,      slotN);
    GLD16(src8B + e0 + 64, slotN + 1024);
    GLD16(src8B + e1,      slotN + 2048);
    GLD16(src8B + e1 + 64, slotN + 3072);
    const int kj = (k + 2 < KOFF) ? k + 2 : KOFF - 1;
    iN = nbr[kj * N_VOX + rme];
    mN = mb[kj * N_VOX + rme];
  }

  // A(k) fragments from own ring slot (linear, conflict-free), zero masked rows
  v8s a0 = *(const v8s*)(slotC + lane * 16);
  v8s a1 = *(const v8s*)(slotC + 1024 + lane * 16);
  v8s a2 = *(const v8s*)(slotC + 2048 + lane * 16);
  v8s a3 = *(const v8s*)(slotC + 3072 + lane * 16);
  if (!mc0) { a0 = (v8s){}; a1 = (v8s){}; }
  if (!mc1) { a2 = (v8s){}; a3 = (v8s){}; }
  mc0 = v0; mc1 = v1;

#pragma unroll
  for (int ct = 0; ct < 4; ++ct) {
    v8s blo = *(const v8s*)(Wb + (ct * 2) * 1024 + lane * 16);
    v8s bhi = *(const v8s*)(Wb + (ct * 2 + 1) * 1024 + lane * 16);
    acc[0][ct] = __builtin_amdgcn_mfma_f32_16x16x32_bf16(a0, blo, acc[0][ct], 0, 0, 0);
    acc[0][ct] = __builtin_amdgcn_mfma_f32_16x16x32_bf16(a1, bhi, acc[0][ct], 0, 0, 0);
    acc[1][ct] = __builtin_amdgcn_mfma_f32_16x16x32_bf16(a2, blo, acc[1][ct], 0, 0, 0);
    acc[1][ct] = __builtin_amdgcn_mfma_f32_16x16x32_bf16(a3, bhi, acc[1][ct], 0, 0, 0);
  }

  if (!last) {
    asm volatile("s_waitcnt lgkmcnt(0)" ::: "memory");
    __builtin_amdgcn_sched_barrier(0);
    __builtin_amdgcn_s_barrier();                    // #1: all W(k)/A(k) reads done
    *(v8s*)(Wb + (wv * 128 + lane) * 16) = w0;       // stage W(k+1) (waits Wreg only)
    *(v8s*)(Wb + (wv * 128 + 64 + lane) * 16) = w1;
    asm volatile("s_waitcnt lgkmcnt(0)" ::: "memory");
    __builtin_amdgcn_sched_barrier(0);
    __builtin_amdgcn_s_barrier();                    // #2: W(k+1) visible
  }
}

// --- one sparse-conv layer: 4 waves x 32 rows, A via E/O GLD16 ring, W via
// reg-staged single LDS buffer. 40KB LDS -> 4 blocks/CU = 16 waves, grid 2048
// = 8 work/CU = 2 exact phases. ---
template <int LAYER>
__global__ __launch_bounds__(256, 4)
void conv_layer_k(const char* __restrict__ src8B, const int* __restrict__ nbr,
                  const unsigned char* __restrict__ mb,
                  const v8s* __restrict__ wfg, const float* __restrict__ bias,
                  const float* __restrict__ resid, void* __restrict__ outp) {
  __shared__ char ldsW[8192];        // W(k), single buffer (reg-staged dbuf in time)
  __shared__ char ldsA[4][2][4096];  // per-wave E/O ring slots
  const int tid = threadIdx.x;
  const int lane = tid & 63;
  const int wv = tid >> 6;
  const int l15 = lane & 15;
  const int g = lane >> 4;
  const int rowbase = blockIdx.x * 128 + wv * 32;
  const int rme = rowbase + (lane & 31);
  char* slotE = ldsA[wv][0];
  char* slotO = ldsA[wv][1];

  // ---- prologue: mirrors the steady-state FIFO ----
  int iN = nbr[rme];
  int mN = mb[rme];
  v8s w0 = wfg[wv * 128 + lane];
  v8s w1 = wfg[wv * 128 + 64 + lane];
  int mc0 = __shfl(mN, l15, 64);
  int mc1 = __shfl(mN, 16 + l15, 64);
  {
    int j0 = __shfl(iN, l15, 64);
    int j1 = __shfl(iN, 16 + l15, 64);
    long e0 = (long)(mc0 ? j0 : 0) * 128 + g * 16;
    long e1 = (long)(mc1 ? j1 : 0) * 128 + g * 16;
    GLD16(src8B + e0,      slotE);
    GLD16(src8B + e0 + 64, slotE + 1024);
    GLD16(src8B + e1,      slotE + 2048);
    GLD16(src8B + e1 + 64, slotE + 3072);
  }
  iN = nbr[N_VOX + rme];
  mN = mb[N_VOX + rme];
  *(v8s*)(ldsW + (wv * 128 + lane) * 16) = w0;
  *(v8s*)(ldsW + (wv * 128 + 64 + lane) * 16) = w1;
  asm volatile("s_waitcnt lgkmcnt(0)" ::: "memory");
  __builtin_amdgcn_sched_barrier(0);
  __builtin_amdgcn_s_barrier();

  v4f acc[2][4] = {};

#pragma unroll 1
  for (int k = 0; k < KOFF - 1; k += 2) {   // bodies 0..25
    conv_body(k,     false, ldsW, slotE, slotO, src8B, wfg, nbr, mb,
              lane, wv, g, l15, rme, iN, mN, mc0, mc1, acc);
    conv_body(k + 1, false, ldsW, slotO, slotE, src8B, wfg, nbr, mb,
              lane, wv, g, l15, rme, iN, mN, mc0, mc1, acc);
  }
  conv_body(KOFF - 1, true, ldsW, slotE, slotO, src8B, wfg, nbr, mb,
            lane, wv, g, l15, rme, iN, mN, mc0, mc1, acc);

  float bv[4];
#pragma unroll
  for (int ct = 0; ct < 4; ++ct) bv[ct] = bias[ct * 16 + l15];

#pragma unroll
  for (int rt = 0; rt < 2; ++rt) {
    int row0 = rowbase + rt * 16 + g * 4;   // D row = (lane>>4)*4 + i
#pragma unroll
    for (int ct = 0; ct < 4; ++ct) {
      int col = ct * 16 + l15;              // D col = lane & 15
#pragma unroll
      for (int i = 0; i < 4; ++i) {
        float v = acc[rt][ct][i] + bv[ct];
        int o = (row0 + i) * CCH + col;
        if (LAYER == 1) ((unsigned short*)outp)[o] = f2bf(v);
        else            ((float*)outp)[o] = v + resid[o];
      }
    }
  }
}

extern "C" void kernel_launch(void* const* d_in, const int* in_sizes, int n_in,
                              void* d_out, int out_size, void* d_ws, size_t ws_size,
                              hipStream_t stream) {
  const float* feat = (const float*)d_in[0];
  const int* nbr    = (const int*)d_in[1];
  const void* mask  = d_in[2];
  const float* w1   = (const float*)d_in[3];
  const float* b1   = (const float*)d_in[4];
  const float* w2   = (const float*)d_in[5];
  const float* b2   = (const float*)d_in[6];

  char* ws = (char*)d_ws;
  unsigned short* featb = (unsigned short*)ws;                    // 33,554,432 B
  unsigned short* hb    = (unsigned short*)(ws + 33554432);       // 33,554,432 B
  unsigned char*  maskb = (unsigned char*)(ws + 67108864);        //  7,077,888 B
  unsigned short* wf1   = (unsigned short*)(ws + 74186752);       //    221,184 B
  unsigned short* wf2   = (unsigned short*)(ws + 74407936);       //    221,184 B
  int*            flag  = (int*)(ws + 74629120);

  prep_flag_k<<<1, 64, 0, stream>>>((const unsigned*)mask, flag);
  prep_mask_k<<<4096, 256, 0, stream>>>(mask, flag, maskb, KOFF * N_VOX);
  prep_feat_k<<<8192, 256, 0, stream>>>(feat, featb, N_VOX * CCH / 8);
  prep_w_k<<<432, 256, 0, stream>>>(w1, wf1);
  prep_w_k<<<432, 256, 0, stream>>>(w2, wf2);

  conv_layer_k<1><<<2048, 256, 0, stream>>>((const char*)featb, nbr, maskb,
                                            (const v8s*)wf1, b1, nullptr, (void*)hb);
  conv_layer_k<2><<<2048, 256, 0, stream>>>((const char*)hb, nbr, maskb,
                                            (const v8s*)wf2, b2, feat, (void*)d_out);
}